// Round 4
// baseline (277.246 us; speedup 1.0000x reference)
//
#include <hip/hip_runtime.h>

// RGCN_70566312673746: out[e,o] = xsum[e] * sum_r (1/cs[e,r]) * Wsum[r,o]
//   Wsum[r,o] = sum_i W[r,i,o].  E=100000, R=64, I=256, O=256.
//   edge_index is UNUSED by the reference output.
//
// Round-4: K1 (wsum -> bf16 Wsum^T in ws) + ONE fused streaming kernel.
//   - W frags pre-swizzled into LDS in MFMA fragment order -> conflict-free
//     ds_read_b128, no 128-VGPR hoist (occupancy up).
//   - xsum computed in-register per wave (2-step shfl_xor butterfly); no
//     xsum buffer, no kernel->kernel dependency.
//   - 782 blocks x 4 waves = 3128 waves; wave v handles exactly tiles v and
//     v+3125 (6250 = 2*3125): perfectly balanced, all blocks co-resident.
//   - cs issued before x so b-frag pack doesn't drain the x loads; nt loads
//     for x/cs, nt stores for out (write-once).

constexpr int En = 100000;
constexpr int Rn = 64;
constexpr int In = 256;
constexpr int On = 256;
constexpr int TILES  = En / 16;     // 6250
constexpr int BLOCKS = 782;         // 3128 waves
constexpr int WAVES  = TILES / 2;   // 3125 active waves, 2 tiles each

typedef short bf16x8 __attribute__((ext_vector_type(8)));
typedef float floatx4 __attribute__((ext_vector_type(4)));

// round-to-nearest-even fp32 -> bf16 bits (finite values only)
static __device__ __forceinline__ short f2bf(float f) {
    unsigned u = __builtin_bit_cast(unsigned, f);
    return (short)((u + 0x7FFFu + ((u >> 16) & 1u)) >> 16);
}

// ---- K1: Wsum^T[o][r] = bf16(sum_i W[r,i,o]).  block b: r=b>>2, o-half h=b&3 ----
__global__ __launch_bounds__(1024) void wsum_kernel(const float* __restrict__ W,
                                                    short* __restrict__ wsumT) {
    __shared__ float red[16][65];
    const int r  = blockIdx.x >> 2;
    const int h  = blockIdx.x & 3;
    const int ol = threadIdx.x & 63;
    const int ic = threadIdx.x >> 6;
    const int o  = h * 64 + ol;
    const float* base = W + ((size_t)r * In + (size_t)ic * 16) * On + o;
    float s = 0.f;
#pragma unroll
    for (int i = 0; i < 16; ++i) s += base[(size_t)i * On];
    red[ic][ol] = s;
    __syncthreads();
    if (ic == 0) {
        float t = 0.f;
#pragma unroll
        for (int j = 0; j < 16; ++j) t += red[j][ol];
        wsumT[o * Rn + r] = f2bf(t);
    }
}

// ---- K2: fused xsum + transposed-MFMA out kernel ----
__global__ __launch_bounds__(256) void fused_kernel(const float* __restrict__ x,
                                                    const float* __restrict__ cs,
                                                    const short* __restrict__ wsumT,
                                                    float* __restrict__ out) {
    // W fragments in MFMA order: entry [half][ot][q][lm] = Wsum^T rows
    // o = ot*16+lm, r = half*32 + q*8 .. +7  (16 B each; 2048 entries = 32 KB)
    __shared__ floatx4 Wf[2048];

    const int t = threadIdx.x;
    {
        const floatx4* wq = (const floatx4*)wsumT;   // 2048 16-B chunks, [o][r/8]
#pragma unroll
        for (int k = 0; k < 8; ++k) {
            const int e    = t + 256 * k;
            const int half = e >> 10;
            const int idx  = e & 1023;
            const int ot   = idx >> 6;
            const int q    = (idx >> 4) & 3;
            const int lm   = idx & 15;
            Wf[e] = wq[(ot * 16 + lm) * 8 + half * 4 + q];
        }
    }
    __syncthreads();   // only barrier; Wf read-only afterwards

    const int ln = t & 63;
    const int lm = ln & 15;   // e-local (MFMA A-row / D-col)
    const int q  = ln >> 4;   // k-subchunk / D-row group
    const int v  = (t >> 6) * BLOCKS + blockIdx.x;   // 0..3127, CU-spread
    if (v >= WAVES) return;

    const bf16x8* WfA = (const bf16x8*)Wf;

#pragma unroll
    for (int pass = 0; pass < 2; ++pass) {
        const int tl = v + pass * WAVES;             // exact: tl < 6250
        const size_t e = (size_t)tl * 16 + lm;       // this lane's entity row

        // -- cs first (so packing b drains only these 4 loads) --
        const floatx4* pc = (const floatx4*)(cs + e * Rn) + q * 2;
        const floatx4 c0 = __builtin_nontemporal_load(pc);
        const floatx4 c1 = __builtin_nontemporal_load(pc + 1);
        const floatx4 c2 = __builtin_nontemporal_load(pc + 8);
        const floatx4 c3 = __builtin_nontemporal_load(pc + 9);

        // -- x loads: lane streams its contiguous 256 B of row e --
        const floatx4* px = (const floatx4*)(x + e * In) + q * 16;
        floatx4 sx = {0.f, 0.f, 0.f, 0.f};
#pragma unroll
        for (int j = 0; j < 16; ++j)
            sx += __builtin_nontemporal_load(px + j);
        float s = (sx[0] + sx[1]) + (sx[2] + sx[3]);
        // butterfly across the 4 lanes sharing lm (lanes lm, lm+16, lm+32, lm+48)
        s += __shfl_xor(s, 16, 64);
        s += __shfl_xor(s, 32, 64);                  // s = xsum[e], fp32

        // -- B frags: B[k=r=half*32+q*8+j][n=lm] = bf16(1/cs[e][r]) --
        bf16x8 b0, b1;
        {
            const float rv[16] = {c0[0], c0[1], c0[2], c0[3], c1[0], c1[1], c1[2], c1[3],
                                  c2[0], c2[1], c2[2], c2[3], c3[0], c3[1], c3[2], c3[3]};
#pragma unroll
            for (int j = 0; j < 8; ++j) {
                b0[j] = f2bf(__builtin_amdgcn_rcpf(rv[j]));
                b1[j] = f2bf(__builtin_amdgcn_rcpf(rv[8 + j]));
            }
        }

        // -- 16 o-tiles: 2 conflict-free ds_read_b128 + 2 MFMA each;
        //    D: row=q*4+rg -> o, col=lm -> e; scale by fp32 xsum; nt store --
        float* orow = out + e * On + q * 4;
#pragma unroll
        for (int ot = 0; ot < 16; ++ot) {
            const bf16x8 wa0 = WfA[ot * 64 + ln];
            const bf16x8 wa1 = WfA[1024 + ot * 64 + ln];
            floatx4 acc = {0.f, 0.f, 0.f, 0.f};
            acc = __builtin_amdgcn_mfma_f32_16x16x32_bf16(wa0, b0, acc, 0, 0, 0);
            acc = __builtin_amdgcn_mfma_f32_16x16x32_bf16(wa1, b1, acc, 0, 0, 0);
            const floatx4 st = acc * s;
            __builtin_nontemporal_store(st, (floatx4*)(orow + ot * 16));
        }
    }
}

extern "C" void kernel_launch(void* const* d_in, const int* in_sizes, int n_in,
                              void* d_out, int out_size, void* d_ws, size_t ws_size,
                              hipStream_t stream) {
    const float* x  = (const float*)d_in[0];   // (E, I) fp32
    const float* cs = (const float*)d_in[1];   // (E, R) fp32
    const float* W  = (const float*)d_in[2];   // (R, I, O) fp32
    // d_in[3] = edge_index: unused by the reference output.
    float* out   = (float*)d_out;
    short* wsumT = (short*)d_ws;               // 32 KB bf16 Wsum^T [o][r]

    wsum_kernel<<<dim3(256), dim3(1024), 0, stream>>>(W, wsumT);
    fused_kernel<<<dim3(BLOCKS), dim3(256), 0, stream>>>(x, cs, wsumT, out);
}